// Round 1
// baseline (289.915 us; speedup 1.0000x reference)
//
#include <hip/hip_runtime.h>
#include <math.h>

#define THREADS 256

// -------------------- zero workspace accumulators --------------------
__global__ void zero_kernel(float* __restrict__ p, int n) {
    int i = blockIdx.x * blockDim.x + threadIdx.x;
    if (i < n) p[i] = 0.f;
}

// -------------------- segment mean-pool (sums + counts) --------------------
// Each block handles a contiguous chunk of one batch's pixels, accumulating
// K*5 bins (fx, fy, xx, yy, count) in LDS, then flushes with global atomics.
__global__ void pool_kernel(const int* __restrict__ labels,
                            const float* __restrict__ fx,
                            const float* __restrict__ fy,
                            float* __restrict__ sums,
                            int K, int H, int W, int chunks_per_batch) {
    extern __shared__ float bins[];            // K*5 floats
    const int P = H * W;
    const int b = blockIdx.x / chunks_per_batch;
    const int chunk = blockIdx.x % chunks_per_batch;
    const int chunkP = P / chunks_per_batch;
    const int tid = threadIdx.x;

    for (int i = tid; i < K * 5; i += blockDim.x) bins[i] = 0.f;
    __syncthreads();

    const float sx = 2.f / (float)(H - 1);     // xx varies along dim 2 (i = p / W)
    const float sy = 2.f / (float)(W - 1);     // yy varies along dim 3 (j = p % W)
    const size_t base = (size_t)b * P + (size_t)chunk * chunkP;
    const int4*   l4p  = (const int4*)(labels + base);
    const float4* fx4p = (const float4*)(fx + base);
    const float4* fy4p = (const float4*)(fy + base);
    const int nvec = chunkP / 4;

    for (int v = tid; v < nvec; v += blockDim.x) {
        int4   l4 = l4p[v];
        float4 f4 = fx4p[v];
        float4 g4 = fy4p[v];
        int p0 = chunk * chunkP + v * 4;       // pixel index within the batch image
        int   ls[4] = {l4.x, l4.y, l4.z, l4.w};
        float fs[4] = {f4.x, f4.y, f4.z, f4.w};
        float gs[4] = {g4.x, g4.y, g4.z, g4.w};
        #pragma unroll
        for (int s = 0; s < 4; ++s) {
            int p = p0 + s;
            int i = p / W;
            int j = p - i * W;
            float xx = (float)i * sx - 1.f;
            float yy = (float)j * sy - 1.f;
            float* bin = bins + ls[s] * 5;
            atomicAdd(bin + 0, fs[s]);
            atomicAdd(bin + 1, gs[s]);
            atomicAdd(bin + 2, xx);
            atomicAdd(bin + 3, yy);
            atomicAdd(bin + 4, 1.f);
        }
    }
    __syncthreads();

    float* out = sums + (size_t)b * K * 5;
    for (int i = tid; i < K * 5; i += blockDim.x) {
        float v = bins[i];
        if (v != 0.f) atomicAdd(out + i, v);
    }
}

// -------------------- layer 1: x[5] @ conv_w.T + conv_b -> h1 [64][N] --------------------
__global__ void layer1_kernel(const float* __restrict__ sums,
                              const int* __restrict__ frame_idx,
                              const int* __restrict__ n_frames_p,
                              const float* __restrict__ conv_w,
                              const float* __restrict__ conv_b,
                              float* __restrict__ h1,
                              int K, int N) {
    __shared__ float w[64 * 5];
    __shared__ float bb[64];
    int tid = threadIdx.x;
    for (int i = tid; i < 64 * 5; i += blockDim.x) w[i] = conv_w[i];
    if (tid < 64) bb[tid] = conv_b[tid];
    __syncthreads();

    int t = blockIdx.x * blockDim.x + tid;
    if (t >= N) return;
    int b = t / K;
    float inv_nf = 1.f / (float)(n_frames_p[0] - 1);
    float x0 = (float)frame_idx[b] * inv_nf;
    const float* s = sums + (size_t)t * 5;
    float inv = 1.f / fmaxf(s[4], 1.f);
    float x1 = s[0] * inv;
    float x2 = s[1] * inv;
    float x3 = s[2] * inv;
    float x4 = s[3] * inv;
    #pragma unroll
    for (int c = 0; c < 64; ++c) {
        const float* wc = w + c * 5;
        float h = bb[c] + wc[0]*x0 + wc[1]*x1 + wc[2]*x2 + wc[3]*x3 + wc[4]*x4;
        h1[(size_t)c * N + t] = h;
    }
}

// -------------------- batch-norm stats -> folded scale/shift --------------------
// One block per channel; h is channel-major [C][N].
__global__ void stats_kernel(const float* __restrict__ h,
                             const float* __restrict__ g,
                             const float* __restrict__ bb,
                             float* __restrict__ scale,
                             float* __restrict__ shift,
                             int N) {
    __shared__ float s_sum[THREADS];
    __shared__ float s_sq[THREADS];
    int c = blockIdx.x;
    const float* row = h + (size_t)c * N;
    float sum = 0.f, sq = 0.f;
    for (int t = threadIdx.x; t < N; t += blockDim.x) {
        float v = row[t];
        sum += v;
        sq  += v * v;
    }
    s_sum[threadIdx.x] = sum;
    s_sq[threadIdx.x]  = sq;
    __syncthreads();
    for (int off = THREADS / 2; off > 0; off >>= 1) {
        if (threadIdx.x < off) {
            s_sum[threadIdx.x] += s_sum[threadIdx.x + off];
            s_sq[threadIdx.x]  += s_sq[threadIdx.x + off];
        }
        __syncthreads();
    }
    if (threadIdx.x == 0) {
        float mean = s_sum[0] / (float)N;
        float var  = s_sq[0] / (float)N - mean * mean;   // biased, matches jnp.var
        float istd = rsqrtf(var + 1e-5f);
        float sc = g[c] * istd;
        scale[c] = sc;
        shift[c] = bb[c] - mean * sc;
    }
}

// -------------------- layer 2: relu(bn1(h1)) @ lin_w.T + lin_b -> h2 [32][N] --------------------
__global__ void layer2_kernel(const float* __restrict__ h1,
                              const float* __restrict__ scale1,
                              const float* __restrict__ shift1,
                              const float* __restrict__ lin_w,
                              const float* __restrict__ lin_b,
                              float* __restrict__ h2,
                              int N) {
    __shared__ float w[32 * 64];
    __shared__ float sc[64], sh[64], lb[32];
    int tid = threadIdx.x;
    for (int i = tid; i < 32 * 64; i += blockDim.x) w[i] = lin_w[i];
    if (tid < 64) { sc[tid] = scale1[tid]; sh[tid] = shift1[tid]; }
    if (tid < 32) lb[tid] = lin_b[tid];
    __syncthreads();

    int t = blockIdx.x * blockDim.x + tid;
    if (t >= N) return;
    float y[64];
    #pragma unroll
    for (int c = 0; c < 64; ++c) {
        float v = h1[(size_t)c * N + t] * sc[c] + sh[c];
        y[c] = fmaxf(v, 0.f);
    }
    #pragma unroll 4
    for (int o = 0; o < 32; ++o) {
        float acc = lb[o];
        const float* wo = w + o * 64;
        #pragma unroll
        for (int c = 0; c < 64; ++c) acc += wo[c] * y[c];
        h2[(size_t)o * N + t] = acc;
    }
}

// -------------------- final: relu(bn2(h2)), L2-normalize rows -> out [N][32] --------------------
__global__ void final_kernel(const float* __restrict__ h2,
                             const float* __restrict__ scale2,
                             const float* __restrict__ shift2,
                             float* __restrict__ out,
                             int N) {
    __shared__ float sc[32], sh[32];
    int tid = threadIdx.x;
    if (tid < 32) { sc[tid] = scale2[tid]; sh[tid] = shift2[tid]; }
    __syncthreads();

    int t = blockIdx.x * blockDim.x + tid;
    if (t >= N) return;
    float y[32];
    float ss = 0.f;
    #pragma unroll
    for (int o = 0; o < 32; ++o) {
        float v = h2[(size_t)o * N + t] * sc[o] + sh[o];
        v = fmaxf(v, 0.f);
        y[o] = v;
        ss += v * v;
    }
    float inv = 1.f / fmaxf(sqrtf(ss), 1e-8f);
    float4* o4 = (float4*)(out + (size_t)t * 32);
    #pragma unroll
    for (int o = 0; o < 8; ++o) {
        o4[o] = make_float4(y[o*4+0]*inv, y[o*4+1]*inv, y[o*4+2]*inv, y[o*4+3]*inv);
    }
}

extern "C" void kernel_launch(void* const* d_in, const int* in_sizes, int n_in,
                              void* d_out, int out_size, void* d_ws, size_t ws_size,
                              hipStream_t stream) {
    const int*   labels     = (const int*)d_in[0];
    const float* fx         = (const float*)d_in[1];
    const float* fy         = (const float*)d_in[2];
    const int*   frame_idx  = (const int*)d_in[3];
    const int*   n_frames_p = (const int*)d_in[4];
    // d_in[5] = n_labels (derived host-side from out_size instead)
    const float* conv_w = (const float*)d_in[6];
    const float* conv_b = (const float*)d_in[7];
    const float* bn1_g  = (const float*)d_in[8];
    const float* bn1_b  = (const float*)d_in[9];
    const float* lin_w  = (const float*)d_in[10];
    const float* lin_b  = (const float*)d_in[11];
    const float* bn2_g  = (const float*)d_in[12];
    const float* bn2_b  = (const float*)d_in[13];
    float* out = (float*)d_out;

    const int B = in_sizes[3];                       // 16
    const int P = in_sizes[0] / B;                   // 262144
    const int W = (int)(sqrt((double)P) + 0.5);      // 512 (square image)
    const int H = P / W;
    const int K = out_size / (B * 32);               // 1024
    const int N = B * K;                             // 16384

    // workspace layout (floats)
    float* sums   = (float*)d_ws;                    // N*5
    float* h1     = sums + (size_t)N * 5;            // 64*N
    float* h2     = h1 + (size_t)64 * N;             // 32*N
    float* scale1 = h2 + (size_t)32 * N;             // 64
    float* shift1 = scale1 + 64;                     // 64
    float* scale2 = shift1 + 64;                     // 32
    float* shift2 = scale2 + 32;                     // 32

    int chunks = 16;
    while (chunks > 1 && (P % (chunks * 4)) != 0) chunks >>= 1;

    zero_kernel<<<(N * 5 + THREADS - 1) / THREADS, THREADS, 0, stream>>>(sums, N * 5);
    pool_kernel<<<B * chunks, THREADS, (size_t)K * 5 * sizeof(float), stream>>>(
        labels, fx, fy, sums, K, H, W, chunks);
    layer1_kernel<<<(N + THREADS - 1) / THREADS, THREADS, 0, stream>>>(
        sums, frame_idx, n_frames_p, conv_w, conv_b, h1, K, N);
    stats_kernel<<<64, THREADS, 0, stream>>>(h1, bn1_g, bn1_b, scale1, shift1, N);
    layer2_kernel<<<(N + THREADS - 1) / THREADS, THREADS, 0, stream>>>(
        h1, scale1, shift1, lin_w, lin_b, h2, N);
    stats_kernel<<<32, THREADS, 0, stream>>>(h2, bn2_g, bn2_b, scale2, shift2, N);
    final_kernel<<<(N + THREADS - 1) / THREADS, THREADS, 0, stream>>>(
        h2, scale2, shift2, out, N);
}